// Round 9
// baseline (545.872 us; speedup 1.0000x reference)
//
#include <hip/hip_runtime.h>

#define VQ_B 32
#define VQ_D 64
#define VQ_L 4096
#define VQ_N 1024
#define VQ_R (VQ_B * VQ_L)            /* 131072 rows */
#define VQ_ZQ ((size_t)VQ_R * VQ_D)   /* 8388608 z_q elements */
#define MAIN_BLOCK 256
#define MAIN_GRID (VQ_R / MAIN_BLOCK) /* 512 (epilogue grid) */
#define NSEG 4
#define SEG_C (VQ_N / NSEG)           /* 256 codes per segment */
#define NT 16                         /* code-tile: 16 accumulators */
#define KC 4                          /* k-chunk: 4 z values live */
#define ROWS 64                       /* rows per block (= lanes) */
#define DGRID (VQ_R / ROWS)           /* 2048 row-blocks */

typedef __attribute__((ext_vector_type(16))) float f32x16;
typedef __attribute__((ext_vector_type(2)))  float v2f;

/* ---- prep kernel: nE (validated pairwise tree) + emb transpose ---- */
#define ZVE(i) ((i) < 16 ? zvA[(i) & 15] : (i) < 32 ? zvB[(i) & 15] \
               : (i) < 48 ? zvC[(i) & 15] : zvD[(i) & 15])
#define SQB(x) ({ float s_ = (x) * (x); asm volatile("" : "+v"(s_)); s_; })
#define NP_PAIRWISE64_SQ(dst)                                                  \
    do {                                                                       \
        float r0 = SQB(ZVE(0)), r1 = SQB(ZVE(1)), r2 = SQB(ZVE(2)),            \
              r3 = SQB(ZVE(3)), r4 = SQB(ZVE(4)), r5 = SQB(ZVE(5)),            \
              r6 = SQB(ZVE(6)), r7 = SQB(ZVE(7));                              \
        _Pragma("unroll")                                                      \
        for (int i_ = 1; i_ < 8; ++i_) {                                       \
            r0 += SQB(ZVE(8 * i_ + 0)); r1 += SQB(ZVE(8 * i_ + 1));            \
            r2 += SQB(ZVE(8 * i_ + 2)); r3 += SQB(ZVE(8 * i_ + 3));            \
            r4 += SQB(ZVE(8 * i_ + 4)); r5 += SQB(ZVE(8 * i_ + 5));            \
            r6 += SQB(ZVE(8 * i_ + 6)); r7 += SQB(ZVE(8 * i_ + 7));            \
        }                                                                      \
        dst = ((r0 + r1) + (r2 + r3)) + ((r4 + r5) + (r6 + r7));               \
    } while (0)

__global__ void vq_prep(const float* __restrict__ emb, float* __restrict__ nE,
                        float* __restrict__ emb_t) {
    const int c = blockIdx.x * blockDim.x + threadIdx.x;
    if (c >= VQ_N) return;
    const float* ec = emb + (c << 6);
    f32x16 zvA, zvB, zvC, zvD;
#pragma unroll
    for (int d = 0; d < 16; ++d) {
        zvA[d] = ec[d];
        zvB[d] = ec[d + 16];
        zvC[d] = ec[d + 32];
        zvD[d] = ec[d + 48];
    }
    float s;
    NP_PAIRWISE64_SQ(s);
    nE[c] = s;
    /* transpose: emb_t[k][c]; per k the 1024 threads write coalesced */
#pragma unroll
    for (int k = 0; k < 16; ++k) {
        emb_t[(k     ) * VQ_N + c] = zvA[k];
        emb_t[(k + 16) * VQ_N + c] = zvB[k];
        emb_t[(k + 32) * VQ_N + c] = zvC[k];
        emb_t[(k + 48) * VQ_N + c] = zvD[k];
    }
}

/* ---- distance kernel: 4 waves share one 64-row z tile ----
   Wave w scans codebook segment w; c0 forced scalar via readfirstlane
   (round 7: without it emb demotes to per-lane VMEM, 2.2x slower).
   Inner loop over emb_t[k][c]: code-adjacent values contiguous ->
   s_load pairs feed v_pk_fma_f32 (packed fp32: TWO independent
   per-code chains per instruction). Each code's chain still gets
   k = 0..63 strictly ascending, single fused accumulator -> bitwise
   identical dist; tie-scan ascending (x before y), strict <. */
__global__ __launch_bounds__(4 * ROWS, 4) void vq_dist(
    const float* __restrict__ z, const float* __restrict__ emb_t,
    const float* __restrict__ nE, float2* __restrict__ cand)
{
    __shared__ float zs[VQ_D * ROWS];  /* 16 KB: [d][lane] */
    const int w = threadIdx.x >> 6;    /* wave = codebook segment */
    const int lane = threadIdx.x & 63;
    const int r = blockIdx.x * ROWS + lane;
    const int b = r >> 12;
    const int l = r & (VQ_L - 1);
    const float* zp = z + ((size_t)b << 18) + l;   /* z[b, d, l], d-stride 4096 */

    /* cooperative stage: wave w loads d in [16w, 16w+16), coalesced */
#pragma unroll
    for (int j = 0; j < 16; ++j) {
        const int d = (w << 4) + j;
        zs[d * ROWS + lane] = zp[(size_t)d << 12];
    }
    __syncthreads();

    /* szz from LDS, numpy 8-acc pairwise order (identical bits) */
    float a8[8];
#pragma unroll
    for (int j = 0; j < 8; ++j) {
        const float v = zs[j * ROWS + lane];
        float s = v * v;
        asm volatile("" : "+v"(s));
        a8[j] = s;
    }
#pragma unroll
    for (int i = 1; i < 8; ++i) {
#pragma unroll
        for (int j = 0; j < 8; ++j) {
            const float v = zs[(8 * i + j) * ROWS + lane];
            float s = v * v;
            asm volatile("" : "+v"(s));
            a8[j] += s;
        }
    }
    const float szz = ((a8[0] + a8[1]) + (a8[2] + a8[3]))
                    + ((a8[4] + a8[5]) + (a8[6] + a8[7]));

    /* SGPR segment base (w is wave-uniform; make it provable) */
    const int c0 = __builtin_amdgcn_readfirstlane(w) * SEG_C;
    float best = __builtin_inff();
    int bc = c0;

    for (int t = 0; t < SEG_C; t += NT) {          /* ascending code tiles */
        v2f acc2[NT / 2];
#pragma unroll
        for (int p = 0; p < NT / 2; ++p) acc2[p] = (v2f){0.0f, 0.0f};

#pragma unroll
        for (int kk = 0; kk < VQ_D; kk += KC) {    /* ascending k chunks */
            const float z0 = zs[(kk + 0) * ROWS + lane];
            const float z1 = zs[(kk + 1) * ROWS + lane];
            const float z2 = zs[(kk + 2) * ROWS + lane];
            const float z3 = zs[(kk + 3) * ROWS + lane];
            const float zk4[KC] = {z0, z1, z2, z3};
#pragma unroll
            for (int k4 = 0; k4 < KC; ++k4) {      /* k strictly ascending */
                const v2f zz = {zk4[k4], zk4[k4]};
                const float* __restrict__ ek = emb_t + (kk + k4) * VQ_N + c0 + t;
#pragma unroll
                for (int p = 0; p < NT / 2; ++p) { /* codes 2p, 2p+1 */
                    const v2f ee = *(const v2f*)(ek + 2 * p);  /* uniform s_load */
                    acc2[p] = __builtin_elementwise_fma(zz, ee, acc2[p]);
                }
            }
        }
#pragma unroll
        for (int p = 0; p < NT / 2; ++p) {         /* ascending: first-index ties */
            const int c = c0 + t + 2 * p;
            const float dx = (szz - 2.0f * acc2[p].x) + nE[c];
            if (dx < best) { best = dx; bc = c; }
            const float dy = (szz - 2.0f * acc2[p].y) + nE[c + 1];
            if (dy < best) { best = dy; bc = c + 1; }
        }
    }
    cand[(size_t)w * VQ_R + r] = make_float2(best, (float)bc);
}

/* ---- merge 4 candidates, gather, write z_q + codes, loss partials ---- */
__global__ __launch_bounds__(MAIN_BLOCK) void vq_epilogue(
    const float* __restrict__ z, const float* __restrict__ emb,
    const float2* __restrict__ cand, float* __restrict__ out,
    float* __restrict__ partials)
{
    const int r = blockIdx.x * MAIN_BLOCK + threadIdx.x;
    const int b = r >> 12;
    const int l = r & (VQ_L - 1);

    float best = __builtin_inff();
    int bc = 0;
#pragma unroll
    for (int seg = 0; seg < NSEG; ++seg) {         /* ascending: ties -> first */
        const float2 cd = cand[(size_t)seg * VQ_R + r];
        if (cd.x < best) { best = cd.x; bc = (int)cd.y; }
    }

    const float* zp = z + ((size_t)b << 18) + l;
    const float* __restrict__ eb = emb + (bc << 6);
    float lsum = 0.0f;
#pragma unroll
    for (int d = 0; d < VQ_D; ++d) {
        const float q = eb[d];
        const float zd = zp[(size_t)d << 12];
        out[((size_t)b << 18) + ((size_t)d << 12) + l] = q;
        const float df = q - zd;
        lsum = __builtin_fmaf(df, df, lsum);
    }
    out[VQ_ZQ + 1 + (size_t)r] = (float)bc;

#pragma unroll
    for (int off = 32; off > 0; off >>= 1)
        lsum += __shfl_down(lsum, off, 64);
    __shared__ float wsum[MAIN_BLOCK / 64];
    const int lane = threadIdx.x & 63;
    const int wid = threadIdx.x >> 6;
    if (lane == 0) wsum[wid] = lsum;
    __syncthreads();
    if (threadIdx.x == 0)
        partials[blockIdx.x] = (wsum[0] + wsum[1]) + (wsum[2] + wsum[3]);
}

__global__ void vq_final(const float* __restrict__ partials, float* __restrict__ out) {
    if (threadIdx.x == 0 && blockIdx.x == 0) {
        float s = 0.0f;
        for (int i = 0; i < MAIN_GRID; ++i) s += partials[i];
        const float mse = s / (float)VQ_ZQ;
        out[VQ_ZQ] = mse + 0.25f * mse;   /* vq_loss + 0.25*commitment */
    }
}

extern "C" void kernel_launch(void* const* d_in, const int* in_sizes, int n_in,
                              void* d_out, int out_size, void* d_ws, size_t ws_size,
                              hipStream_t stream) {
    const float* z   = (const float*)d_in[0];
    const float* emb = (const float*)d_in[1];
    float* out = (float*)d_out;
    float* nE = (float*)d_ws;                        /* 1024 f   @ 0       */
    float* partials = nE + VQ_N;                     /* 512 f    @ 4096B   */
    float2* cand = (float2*)(partials + MAIN_GRID);  /* 4*R f2   @ 6144B   */
    float* emb_t = (float*)(cand + (size_t)NSEG * VQ_R); /* 64K f @ ~4.2MB */

    vq_prep<<<dim3(VQ_N / 256), dim3(256), 0, stream>>>(emb, nE, emb_t);
    vq_dist<<<dim3(DGRID), dim3(4 * ROWS), 0, stream>>>(z, emb_t, nE, cand);
    vq_epilogue<<<dim3(MAIN_GRID), dim3(MAIN_BLOCK), 0, stream>>>(z, emb, cand, out, partials);
    vq_final<<<dim3(1), dim3(64), 0, stream>>>(partials, out);
}

// Round 11
// 322.869 us; speedup vs baseline: 1.6907x; 1.6907x over previous
//
#include <hip/hip_runtime.h>

#define VQ_B 32
#define VQ_D 64
#define VQ_L 4096
#define VQ_N 1024
#define VQ_R (VQ_B * VQ_L)            /* 131072 rows */
#define VQ_ZQ ((size_t)VQ_R * VQ_D)   /* 8388608 z_q elements */
#define MAIN_BLOCK 256
#define MAIN_GRID (VQ_R / MAIN_BLOCK) /* 512 */
#define CAND_CAP 16
#define EPSREL 4.5e-3f                /* >= 2^-7.98 true bf16-mfma bound */

typedef __attribute__((ext_vector_type(16))) float f32x16;
typedef __attribute__((ext_vector_type(8)))  short short8;   /* 8 bf16 */
typedef __attribute__((ext_vector_type(4)))  float f32x4;
typedef __attribute__((ext_vector_type(4)))  unsigned int u32x4;

/* ---------- monotone float<->u32 keys ---------- */
__device__ __forceinline__ unsigned fmono(float x) {
    unsigned u = __builtin_bit_cast(unsigned, x);
    return (u & 0x80000000u) ? ~u : (u | 0x80000000u);
}
__device__ __forceinline__ float fmono_dec(unsigned k) {
    unsigned u = (k & 0x80000000u) ? (k & 0x7FFFFFFFu) : ~k;
    return __builtin_bit_cast(float, u);
}
__device__ __forceinline__ unsigned short f2bf(float x) {
    __bf16 h = (__bf16)x;  /* RNE */
    return __builtin_bit_cast(unsigned short, h);
}

/* ---------- validated numpy-pairwise norm machinery ---------- */
#define ZVE(i) ((i) < 16 ? zvA[(i) & 15] : (i) < 32 ? zvB[(i) & 15] \
               : (i) < 48 ? zvC[(i) & 15] : zvD[(i) & 15])
#define SQB(x) ({ float s_ = (x) * (x); asm volatile("" : "+v"(s_)); s_; })
#define NP_PAIRWISE64_SQ(dst)                                                  \
    do {                                                                       \
        float r0 = SQB(ZVE(0)), r1 = SQB(ZVE(1)), r2 = SQB(ZVE(2)),            \
              r3 = SQB(ZVE(3)), r4 = SQB(ZVE(4)), r5 = SQB(ZVE(5)),            \
              r6 = SQB(ZVE(6)), r7 = SQB(ZVE(7));                              \
        _Pragma("unroll")                                                      \
        for (int i_ = 1; i_ < 8; ++i_) {                                       \
            r0 += SQB(ZVE(8 * i_ + 0)); r1 += SQB(ZVE(8 * i_ + 1));            \
            r2 += SQB(ZVE(8 * i_ + 2)); r3 += SQB(ZVE(8 * i_ + 3));            \
            r4 += SQB(ZVE(8 * i_ + 4)); r5 += SQB(ZVE(8 * i_ + 5));            \
            r6 += SQB(ZVE(8 * i_ + 6)); r7 += SQB(ZVE(8 * i_ + 7));            \
        }                                                                      \
        dst = ((r0 + r1) + (r2 + r3)) + ((r4 + r5) + (r6 + r7));               \
    } while (0)

/* ---------- init: rowcnt=0, nEmax=0 ---------- */
__global__ void vq_init(unsigned* __restrict__ rowcnt, unsigned* __restrict__ nEmax) {
    const int i = blockIdx.x * blockDim.x + threadIdx.x;
    if (i < VQ_R) rowcnt[i] = 0u;
    if (i == 0) *nEmax = 0u;
}

/* ---------- prep emb: exact nE (np chain), emb->bf16, nEmax ---------- */
__global__ void vq_prep_emb(const float* __restrict__ emb, float* __restrict__ nE,
                            unsigned short* __restrict__ emb_bf,
                            unsigned* __restrict__ nEmax) {
    const int c = blockIdx.x * blockDim.x + threadIdx.x;
    if (c >= VQ_N) return;
    const float* ec = emb + (c << 6);
    f32x16 zvA, zvB, zvC, zvD;
#pragma unroll
    for (int d = 0; d < 16; ++d) {
        zvA[d] = ec[d];
        zvB[d] = ec[d + 16];
        zvC[d] = ec[d + 32];
        zvD[d] = ec[d + 48];
    }
    float s;
    NP_PAIRWISE64_SQ(s);
    nE[c] = s;
    atomicMax(nEmax, fmono(s));
#pragma unroll
    for (int d = 0; d < 64; ++d) emb_bf[(c << 6) + d] = f2bf(ec[d]);
}

/* ---------- prep z: row-major bf16 (ALL 64 elems) + fp32 srow ----------
   ROUND-10 BUG: loop covered only k=0..31 -> z_bf[32..63] was garbage and
   srow half-sized. Now j8 in [0,8): 8 chunks x 8 values = 64. */
__global__ __launch_bounds__(256) void vq_prep_z(
    const float* __restrict__ z, unsigned short* __restrict__ z_bf,
    float* __restrict__ srow) {
    const int r = blockIdx.x * 256 + threadIdx.x;
    const int b = r >> 12;
    const int l = r & (VQ_L - 1);
    const float* zp = z + ((size_t)b << 18) + l;
    unsigned short* o = z_bf + ((size_t)r << 6);
    float s = 0.0f;
#pragma unroll
    for (int j8 = 0; j8 < 8; ++j8) {
        unsigned w[4];
#pragma unroll
        for (int p = 0; p < 4; ++p) {
            const float v0 = zp[(size_t)(j8 * 8 + 2 * p) << 12];
            const float v1 = zp[(size_t)(j8 * 8 + 2 * p + 1) << 12];
            s = __builtin_fmaf(v0, v0, s);
            s = __builtin_fmaf(v1, v1, s);
            w[p] = (unsigned)f2bf(v0) | ((unsigned)f2bf(v1) << 16);
        }
        *(u32x4*)(o + j8 * 8) = (u32x4){w[0], w[1], w[2], w[3]};
    }
    srow[r] = s;
}

/* ---------- MFMA screen: g~ = nE - 2*(bf16 dot) for all (row,code) ----
   Wave handles 16 rows x all 1024 codes. A lane: z_bf[rowbase+(lane&15)]
   [k=(lane>>4)*8+e] (16B load). B lane: emb_bf[ct*16+(lane&15)][same k].
   C layout (m89-verified): col=lane&15 (2nd operand row), row=(lane>>4)*4
   +reg (1st operand row). PASS1: per-row min(g~), plain store. PASS2:
   identical g~ bits; emit codes with g~ <= thr[row]. */
template <int PASS>
__global__ __launch_bounds__(256) void vq_gemm(
    const unsigned short* __restrict__ z_bf, const unsigned short* __restrict__ emb_bf,
    const float* __restrict__ nE, const float* __restrict__ thr,
    unsigned* __restrict__ rowmin, unsigned* __restrict__ rowcnt,
    unsigned short* __restrict__ candrow) {
    __shared__ float neS[VQ_N];
    const int tid = threadIdx.x;
    for (int i = tid; i < VQ_N; i += 256) neS[i] = nE[i];
    __syncthreads();

    const int w = tid >> 6, lane = tid & 63;
    const int cl = lane & 15, grp = lane >> 4;
    const int rowbase = blockIdx.x * 64 + w * 16;
    const unsigned short* za = z_bf + ((size_t)(rowbase + cl) << 6) + grp * 8;
    const short8 a0 = *(const short8*)(za);
    const short8 a1 = *(const short8*)(za + 32);

    int   row_r[4];
    float thr_r[4];
#pragma unroll
    for (int reg = 0; reg < 4; ++reg) {
        row_r[reg] = rowbase + grp * 4 + reg;
        thr_r[reg] = (PASS == 2) ? thr[row_r[reg]] : 0.0f;
    }
    float m[4] = {__builtin_inff(), __builtin_inff(), __builtin_inff(), __builtin_inff()};

    for (int ct = 0; ct < VQ_N / 16; ++ct) {
        const int c = ct * 16 + cl;
        const unsigned short* eb = emb_bf + ((size_t)c << 6) + grp * 8;
        const short8 b0 = *(const short8*)(eb);
        const short8 b1 = *(const short8*)(eb + 32);
        f32x4 acc = {0.0f, 0.0f, 0.0f, 0.0f};
        acc = __builtin_amdgcn_mfma_f32_16x16x32_bf16(a0, b0, acc, 0, 0, 0);
        acc = __builtin_amdgcn_mfma_f32_16x16x32_bf16(a1, b1, acc, 0, 0, 0);
        const float ne = neS[c];
#pragma unroll
        for (int reg = 0; reg < 4; ++reg) {
            float g = __builtin_fmaf(-2.0f, acc[reg], ne);
            asm volatile("" : "+v"(g));           /* pin: identical bits both passes */
            if (PASS == 1) {
                m[reg] = fminf(m[reg], g);
            } else if (g <= thr_r[reg]) {
                const unsigned idx = atomicAdd(&rowcnt[row_r[reg]], 1u);
                if (idx < CAND_CAP) candrow[(size_t)row_r[reg] * CAND_CAP + idx] = (unsigned short)c;
            }
        }
    }
    if (PASS == 1) {
#pragma unroll
        for (int reg = 0; reg < 4; ++reg) {
            float v = m[reg];
            v = fminf(v, __shfl_xor(v, 1));
            v = fminf(v, __shfl_xor(v, 2));
            v = fminf(v, __shfl_xor(v, 4));
            v = fminf(v, __shfl_xor(v, 8));
            if (cl == 0) rowmin[row_r[reg]] = fmono(v);
        }
    }
}

/* ---------- thresholds: thr = gmin + rigorous margin ----------
   |g~ - g| <= 2 * (2*2^-8 + 2^-16) * ||z|| * ||e||  (bf16 RNE on both
   operands; fp32 accum error negligible at this scale). margin covers
   2x that bound plus the ulp(64)-scale D-vs-g reordering slack. */
__global__ void vq_thr(const unsigned* __restrict__ rowmin, const float* __restrict__ srow,
                       const unsigned* __restrict__ nEmax, float* __restrict__ thr) {
    const int r = blockIdx.x * blockDim.x + threadIdx.x;
    if (r >= VQ_R) return;
    const float nem = fmono_dec(*nEmax);
    const float margin = 8.0f * EPSREL * sqrtf(srow[r] * nem) + 2e-4f;
    thr[r] = fmono_dec(rowmin[r]) + margin;
}

/* ---------- exact phase: bit-exact D for survivors, pick (D,c)-min ----
   Per thread = one row. szz via validated np pairwise (original fp32 z),
   dot via ascending single-acc fmaf chain (original fp32 emb), combine
   (szz - 2*dot) + nE. Key = mono(D)<<32 | c -> min == strict-< first
   index. Overflowed rows: full 1024-code exact scan. Fused epilogue:
   z_q write, codes write, loss partials (validated). */
__global__ __launch_bounds__(MAIN_BLOCK) void vq_exact(
    const float* __restrict__ z, const float* __restrict__ emb,
    const float* __restrict__ nE, const unsigned* __restrict__ rowcnt,
    const unsigned short* __restrict__ candrow, float* __restrict__ out,
    float* __restrict__ partials) {
    const int r = blockIdx.x * MAIN_BLOCK + threadIdx.x;
    const int b = r >> 12;
    const int l = r & (VQ_L - 1);
    const float* zp = z + ((size_t)b << 18) + l;

    /* szz: numpy pairwise (8 accs, d=8i+j ascending, squares pre-rounded) */
    float a8[8];
#pragma unroll
    for (int j = 0; j < 8; ++j) {
        const float v = zp[(size_t)j << 12];
        float s = v * v;
        asm volatile("" : "+v"(s));
        a8[j] = s;
    }
#pragma unroll
    for (int i = 1; i < 8; ++i) {
#pragma unroll
        for (int j = 0; j < 8; ++j) {
            const float v = zp[(size_t)(8 * i + j) << 12];
            float s = v * v;
            asm volatile("" : "+v"(s));
            a8[j] += s;
        }
    }
    const float szz = ((a8[0] + a8[1]) + (a8[2] + a8[3]))
                    + ((a8[4] + a8[5]) + (a8[6] + a8[7]));

    unsigned long long best = ~0ull;
    const unsigned cnt = rowcnt[r];
    if (cnt >= 1u && cnt <= (unsigned)CAND_CAP) {
        for (unsigned i = 0; i < cnt; ++i) {
            const int c = candrow[(size_t)r * CAND_CAP + i];
            const float* __restrict__ ec = emb + (c << 6);
            float acc = 0.0f;
#pragma unroll
            for (int k = 0; k < VQ_D; ++k)
                acc = __builtin_fmaf(zp[(size_t)k << 12], ec[k], acc);
            const float D = (szz - 2.0f * acc) + nE[c];
            const unsigned long long key = ((unsigned long long)fmono(D) << 32) | (unsigned)c;
            best = (key < best) ? key : best;
        }
    } else {  /* overflow or anomaly: validated full exact scan */
        for (int c = 0; c < VQ_N; ++c) {
            const float* __restrict__ ec = emb + (c << 6);
            float acc = 0.0f;
#pragma unroll
            for (int k = 0; k < VQ_D; ++k)
                acc = __builtin_fmaf(zp[(size_t)k << 12], ec[k], acc);
            const float D = (szz - 2.0f * acc) + nE[c];
            const unsigned long long key = ((unsigned long long)fmono(D) << 32) | (unsigned)c;
            best = (key < best) ? key : best;
        }
    }
    const int bc = (int)(best & 0xFFFFFFFFull);

    const float* __restrict__ eb = emb + (bc << 6);
    float lsum = 0.0f;
#pragma unroll
    for (int d = 0; d < VQ_D; ++d) {
        const float q = eb[d];
        const float zd = zp[(size_t)d << 12];
        out[((size_t)b << 18) + ((size_t)d << 12) + l] = q;
        const float df = q - zd;
        lsum = __builtin_fmaf(df, df, lsum);
    }
    out[VQ_ZQ + 1 + (size_t)r] = (float)bc;

#pragma unroll
    for (int off = 32; off > 0; off >>= 1)
        lsum += __shfl_down(lsum, off, 64);
    __shared__ float wsum[MAIN_BLOCK / 64];
    const int lane = threadIdx.x & 63;
    const int wid = threadIdx.x >> 6;
    if (lane == 0) wsum[wid] = lsum;
    __syncthreads();
    if (threadIdx.x == 0)
        partials[blockIdx.x] = (wsum[0] + wsum[1]) + (wsum[2] + wsum[3]);
}

__global__ void vq_final(const float* __restrict__ partials, float* __restrict__ out) {
    if (threadIdx.x == 0 && blockIdx.x == 0) {
        float s = 0.0f;
        for (int i = 0; i < MAIN_GRID; ++i) s += partials[i];
        const float mse = s / (float)VQ_ZQ;
        out[VQ_ZQ] = mse + 0.25f * mse;
    }
}

/* ================= fallback path (round-8, validated, ~335us) ========== */
__global__ void vq_norme_fb(const float* __restrict__ emb, float* __restrict__ nEf) {
    const int c = blockIdx.x * blockDim.x + threadIdx.x;
    if (c >= VQ_N) return;
    const float* ec = emb + (c << 6);
    f32x16 zvA, zvB, zvC, zvD;
#pragma unroll
    for (int d = 0; d < 16; ++d) {
        zvA[d] = ec[d]; zvB[d] = ec[d + 16]; zvC[d] = ec[d + 32]; zvD[d] = ec[d + 48];
    }
    float s;
    NP_PAIRWISE64_SQ(s);
    nEf[c] = s;
}
__global__ __launch_bounds__(256, 4) void vq_dist_fb(
    const float* __restrict__ z, const float* __restrict__ emb,
    const float* __restrict__ nEf, float2* __restrict__ cand) {
    __shared__ float zs[VQ_D * 64];
    const int w = threadIdx.x >> 6;
    const int lane = threadIdx.x & 63;
    const int r = blockIdx.x * 64 + lane;
    const int b = r >> 12;
    const int l = r & (VQ_L - 1);
    const float* zp = z + ((size_t)b << 18) + l;
#pragma unroll
    for (int j = 0; j < 16; ++j) {
        const int d = (w << 4) + j;
        zs[d * 64 + lane] = zp[(size_t)d << 12];
    }
    __syncthreads();
    float a8[8];
#pragma unroll
    for (int j = 0; j < 8; ++j) {
        const float v = zs[j * 64 + lane];
        float s = v * v; asm volatile("" : "+v"(s)); a8[j] = s;
    }
#pragma unroll
    for (int i = 1; i < 8; ++i) {
#pragma unroll
        for (int j = 0; j < 8; ++j) {
            const float v = zs[(8 * i + j) * 64 + lane];
            float s = v * v; asm volatile("" : "+v"(s)); a8[j] += s;
        }
    }
    const float szz = ((a8[0] + a8[1]) + (a8[2] + a8[3])) + ((a8[4] + a8[5]) + (a8[6] + a8[7]));
    const int c0 = __builtin_amdgcn_readfirstlane(w) * 256;
    float best = __builtin_inff();
    int bc = c0;
    for (int t = 0; t < 256; t += 16) {
        float acc[16];
#pragma unroll
        for (int j = 0; j < 16; ++j) acc[j] = 0.0f;
#pragma unroll
        for (int kk = 0; kk < VQ_D; kk += 4) {
            const float z0 = zs[(kk + 0) * 64 + lane];
            const float z1 = zs[(kk + 1) * 64 + lane];
            const float z2 = zs[(kk + 2) * 64 + lane];
            const float z3 = zs[(kk + 3) * 64 + lane];
#pragma unroll
            for (int j = 0; j < 16; ++j) {
                const float* __restrict__ ec = emb + ((c0 + t + j) << 6) + kk;
                acc[j] = __builtin_fmaf(z0, ec[0], acc[j]);
                acc[j] = __builtin_fmaf(z1, ec[1], acc[j]);
                acc[j] = __builtin_fmaf(z2, ec[2], acc[j]);
                acc[j] = __builtin_fmaf(z3, ec[3], acc[j]);
            }
        }
#pragma unroll
        for (int j = 0; j < 16; ++j) {
            const int c = c0 + t + j;
            const float dist = (szz - 2.0f * acc[j]) + nEf[c];
            if (dist < best) { best = dist; bc = c; }
        }
    }
    cand[(size_t)w * VQ_R + r] = make_float2(best, (float)bc);
}
__global__ __launch_bounds__(MAIN_BLOCK) void vq_epilogue_fb(
    const float* __restrict__ z, const float* __restrict__ emb,
    const float2* __restrict__ cand, float* __restrict__ out,
    float* __restrict__ partials) {
    const int r = blockIdx.x * MAIN_BLOCK + threadIdx.x;
    const int b = r >> 12;
    const int l = r & (VQ_L - 1);
    float best = __builtin_inff();
    int bc = 0;
#pragma unroll
    for (int seg = 0; seg < 4; ++seg) {
        const float2 cd = cand[(size_t)seg * VQ_R + r];
        if (cd.x < best) { best = cd.x; bc = (int)cd.y; }
    }
    const float* zp = z + ((size_t)b << 18) + l;
    const float* __restrict__ eb = emb + (bc << 6);
    float lsum = 0.0f;
#pragma unroll
    for (int d = 0; d < VQ_D; ++d) {
        const float q = eb[d];
        const float zd = zp[(size_t)d << 12];
        out[((size_t)b << 18) + ((size_t)d << 12) + l] = q;
        const float df = q - zd;
        lsum = __builtin_fmaf(df, df, lsum);
    }
    out[VQ_ZQ + 1 + (size_t)r] = (float)bc;
#pragma unroll
    for (int off = 32; off > 0; off >>= 1)
        lsum += __shfl_down(lsum, off, 64);
    __shared__ float wsum[MAIN_BLOCK / 64];
    const int lane = threadIdx.x & 63;
    const int wid = threadIdx.x >> 6;
    if (lane == 0) wsum[wid] = lsum;
    __syncthreads();
    if (threadIdx.x == 0)
        partials[blockIdx.x] = (wsum[0] + wsum[1]) + (wsum[2] + wsum[3]);
}

/* ================= launch ================= */
extern "C" void kernel_launch(void* const* d_in, const int* in_sizes, int n_in,
                              void* d_out, int out_size, void* d_ws, size_t ws_size,
                              hipStream_t stream) {
    const float* z   = (const float*)d_in[0];
    const float* emb = (const float*)d_in[1];
    float* out = (float*)d_out;
    char* ws = (char*)d_ws;

    /* layout (16B-aligned) */
    unsigned short* z_bf   = (unsigned short*)(ws);                       /* 16777216 B */
    unsigned short* emb_bf = (unsigned short*)(ws + 16777216);            /*   131072 B */
    unsigned short* candrw = (unsigned short*)(ws + 16908288);            /*  4194304 B */
    unsigned*       rowmin = (unsigned*)(ws + 21102592);                  /*   524288 B */
    float*          thr    = (float*)(ws + 21626880);                     /*   524288 B */
    float*          srow   = (float*)(ws + 22151168);                     /*   524288 B */
    unsigned*       rowcnt = (unsigned*)(ws + 22675456);                  /*   524288 B */
    float*          nE     = (float*)(ws + 23199744);                     /*     4096 B */
    float*          parts  = (float*)(ws + 23203840);                     /*     2048 B */
    unsigned*       nEmax  = (unsigned*)(ws + 23205888);                  /*        4 B */
    const size_t need = 23205952;

    if (ws_size >= need) {
        vq_init<<<dim3(512), dim3(256), 0, stream>>>(rowcnt, nEmax);
        vq_prep_emb<<<dim3(4), dim3(256), 0, stream>>>(emb, nE, emb_bf, nEmax);
        vq_prep_z<<<dim3(512), dim3(256), 0, stream>>>(z, z_bf, srow);
        vq_gemm<1><<<dim3(VQ_R / 64), dim3(256), 0, stream>>>(z_bf, emb_bf, nE, thr,
                                                              rowmin, rowcnt, candrw);
        vq_thr<<<dim3(512), dim3(256), 0, stream>>>(rowmin, srow, nEmax, thr);
        vq_gemm<2><<<dim3(VQ_R / 64), dim3(256), 0, stream>>>(z_bf, emb_bf, nE, thr,
                                                              rowmin, rowcnt, candrw);
        vq_exact<<<dim3(MAIN_GRID), dim3(MAIN_BLOCK), 0, stream>>>(z, emb, nE, rowcnt,
                                                                   candrw, out, parts);
        vq_final<<<dim3(1), dim3(64), 0, stream>>>(parts, out);
    } else {
        /* validated round-8 fallback (~4.2 MB ws) */
        float* nEf = (float*)ws;
        float* partials = nEf + VQ_N;
        float2* cand = (float2*)(partials + MAIN_GRID);
        vq_norme_fb<<<dim3(4), dim3(256), 0, stream>>>(emb, nEf);
        vq_dist_fb<<<dim3(VQ_R / 64), dim3(256), 0, stream>>>(z, emb, nEf, cand);
        vq_epilogue_fb<<<dim3(MAIN_GRID), dim3(MAIN_BLOCK), 0, stream>>>(z, emb, cand, out, partials);
        vq_final<<<dim3(1), dim3(64), 0, stream>>>(partials, out);
    }
}

// Round 12
// 223.628 us; speedup vs baseline: 2.4410x; 1.4438x over previous
//
#include <hip/hip_runtime.h>

#define VQ_B 32
#define VQ_D 64
#define VQ_L 4096
#define VQ_N 1024
#define VQ_R (VQ_B * VQ_L)            /* 131072 rows */
#define VQ_ZQ ((size_t)VQ_R * VQ_D)   /* 8388608 z_q elements */
#define MAIN_BLOCK 256
#define MAIN_GRID (VQ_R / MAIN_BLOCK) /* 512 */
#define CAND_CAP 16
#define EPSREL 4.5e-3f                /* >= 2^-7.98 true bf16-mfma bound */
#define RT 4                          /* row-tiles per wave (64 rows) */

typedef __attribute__((ext_vector_type(16))) float f32x16;
typedef __attribute__((ext_vector_type(8)))  short short8;   /* 8 bf16 */
typedef __attribute__((ext_vector_type(4)))  float f32x4;
typedef __attribute__((ext_vector_type(4)))  unsigned int u32x4;

/* ---------- monotone float<->u32 keys ---------- */
__device__ __forceinline__ unsigned fmono(float x) {
    unsigned u = __builtin_bit_cast(unsigned, x);
    return (u & 0x80000000u) ? ~u : (u | 0x80000000u);
}
__device__ __forceinline__ float fmono_dec(unsigned k) {
    unsigned u = (k & 0x80000000u) ? (k & 0x7FFFFFFFu) : ~k;
    return __builtin_bit_cast(float, u);
}
__device__ __forceinline__ unsigned short f2bf(float x) {
    __bf16 h = (__bf16)x;  /* RNE */
    return __builtin_bit_cast(unsigned short, h);
}

/* ---------- validated numpy-pairwise norm machinery ---------- */
#define ZVE(i) ((i) < 16 ? zvA[(i) & 15] : (i) < 32 ? zvB[(i) & 15] \
               : (i) < 48 ? zvC[(i) & 15] : zvD[(i) & 15])
#define SQB(x) ({ float s_ = (x) * (x); asm volatile("" : "+v"(s_)); s_; })
#define NP_PAIRWISE64_SQ(dst)                                                  \
    do {                                                                       \
        float r0 = SQB(ZVE(0)), r1 = SQB(ZVE(1)), r2 = SQB(ZVE(2)),            \
              r3 = SQB(ZVE(3)), r4 = SQB(ZVE(4)), r5 = SQB(ZVE(5)),            \
              r6 = SQB(ZVE(6)), r7 = SQB(ZVE(7));                              \
        _Pragma("unroll")                                                      \
        for (int i_ = 1; i_ < 8; ++i_) {                                       \
            r0 += SQB(ZVE(8 * i_ + 0)); r1 += SQB(ZVE(8 * i_ + 1));            \
            r2 += SQB(ZVE(8 * i_ + 2)); r3 += SQB(ZVE(8 * i_ + 3));            \
            r4 += SQB(ZVE(8 * i_ + 4)); r5 += SQB(ZVE(8 * i_ + 5));            \
            r6 += SQB(ZVE(8 * i_ + 6)); r7 += SQB(ZVE(8 * i_ + 7));            \
        }                                                                      \
        dst = ((r0 + r1) + (r2 + r3)) + ((r4 + r5) + (r6 + r7));               \
    } while (0)

/* ---------- init: rowcnt=0, nEmax=0 ---------- */
__global__ void vq_init(unsigned* __restrict__ rowcnt, unsigned* __restrict__ nEmax) {
    const int i = blockIdx.x * blockDim.x + threadIdx.x;
    if (i < VQ_R) rowcnt[i] = 0u;
    if (i == 0) *nEmax = 0u;
}

/* ---------- prep emb: exact nE (np chain), emb->bf16, nEmax ---------- */
__global__ void vq_prep_emb(const float* __restrict__ emb, float* __restrict__ nE,
                            unsigned short* __restrict__ emb_bf,
                            unsigned* __restrict__ nEmax) {
    const int c = blockIdx.x * blockDim.x + threadIdx.x;
    if (c >= VQ_N) return;
    const float* ec = emb + (c << 6);
    f32x16 zvA, zvB, zvC, zvD;
#pragma unroll
    for (int d = 0; d < 16; ++d) {
        zvA[d] = ec[d];
        zvB[d] = ec[d + 16];
        zvC[d] = ec[d + 32];
        zvD[d] = ec[d + 48];
    }
    float s;
    NP_PAIRWISE64_SQ(s);
    nE[c] = s;
    atomicMax(nEmax, fmono(s));
#pragma unroll
    for (int d = 0; d < 64; ++d) emb_bf[(c << 6) + d] = f2bf(ec[d]);
}

/* ---------- prep z: row-major bf16 (all 64 elems) + fp32 srow ---------- */
__global__ __launch_bounds__(256) void vq_prep_z(
    const float* __restrict__ z, unsigned short* __restrict__ z_bf,
    float* __restrict__ srow) {
    const int r = blockIdx.x * 256 + threadIdx.x;
    const int b = r >> 12;
    const int l = r & (VQ_L - 1);
    const float* zp = z + ((size_t)b << 18) + l;
    unsigned short* o = z_bf + ((size_t)r << 6);
    float s = 0.0f;
#pragma unroll
    for (int j8 = 0; j8 < 8; ++j8) {
        unsigned w[4];
#pragma unroll
        for (int p = 0; p < 4; ++p) {
            const float v0 = zp[(size_t)(j8 * 8 + 2 * p) << 12];
            const float v1 = zp[(size_t)(j8 * 8 + 2 * p + 1) << 12];
            s = __builtin_fmaf(v0, v0, s);
            s = __builtin_fmaf(v1, v1, s);
            w[p] = (unsigned)f2bf(v0) | ((unsigned)f2bf(v1) << 16);
        }
        *(u32x4*)(o + j8 * 8) = (u32x4){w[0], w[1], w[2], w[3]};
    }
    srow[r] = s;
}

/* ---------- MFMA screen, 4x B-reuse ----------
   Wave handles 64 rows (RT=4 A-fragment tiles, registers) x 1024 codes.
   Per 16-code tile: ONE b0/b1 load pair feeds 8 MFMAs (was 2) -> VMEM
   requests per FLOP /4 (round-11 bottleneck: MfmaUtil 5%, all pipes idle).
   C layout (m89-verified): col=lane&15 (code), row=(lane>>4)*4+reg.
   PASS1: per-row min(g~). PASS2: identical g~ bits (same MFMA sequence +
   pinned fmaf), emit codes with g~ <= thr[row]. */
template <int PASS>
__global__ __launch_bounds__(256, 2) void vq_gemm(
    const unsigned short* __restrict__ z_bf, const unsigned short* __restrict__ emb_bf,
    const float* __restrict__ nE, const float* __restrict__ thr,
    unsigned* __restrict__ rowmin, unsigned* __restrict__ rowcnt,
    unsigned short* __restrict__ candrow) {
    __shared__ float neS[VQ_N];
    const int tid = threadIdx.x;
    for (int i = tid; i < VQ_N; i += 256) neS[i] = nE[i];
    __syncthreads();

    const int w = tid >> 6, lane = tid & 63;
    const int cl = lane & 15, grp = lane >> 4;
    const int rowbase = blockIdx.x * (64 * RT) + w * (16 * RT);

    short8 a0[RT], a1[RT];
#pragma unroll
    for (int t = 0; t < RT; ++t) {
        const unsigned short* za = z_bf + ((size_t)(rowbase + t * 16 + cl) << 6) + grp * 8;
        a0[t] = *(const short8*)(za);
        a1[t] = *(const short8*)(za + 32);
    }

    int   row_r[RT][4];
    float thr_r[RT][4];
#pragma unroll
    for (int t = 0; t < RT; ++t)
#pragma unroll
        for (int reg = 0; reg < 4; ++reg) {
            row_r[t][reg] = rowbase + t * 16 + grp * 4 + reg;
            thr_r[t][reg] = (PASS == 2) ? thr[row_r[t][reg]] : 0.0f;
        }

    float m[RT][4];
#pragma unroll
    for (int t = 0; t < RT; ++t)
#pragma unroll
        for (int reg = 0; reg < 4; ++reg) m[t][reg] = __builtin_inff();

    for (int ct = 0; ct < VQ_N / 16; ++ct) {
        const int c = ct * 16 + cl;
        const unsigned short* eb = emb_bf + ((size_t)c << 6) + grp * 8;
        const short8 b0 = *(const short8*)(eb);
        const short8 b1 = *(const short8*)(eb + 32);
        const float ne = neS[c];

        f32x4 acc[RT];
#pragma unroll
        for (int t = 0; t < RT; ++t) {
            acc[t] = (f32x4){0.0f, 0.0f, 0.0f, 0.0f};
            acc[t] = __builtin_amdgcn_mfma_f32_16x16x32_bf16(a0[t], b0, acc[t], 0, 0, 0);
            acc[t] = __builtin_amdgcn_mfma_f32_16x16x32_bf16(a1[t], b1, acc[t], 0, 0, 0);
        }
#pragma unroll
        for (int t = 0; t < RT; ++t) {
#pragma unroll
            for (int reg = 0; reg < 4; ++reg) {
                float g = __builtin_fmaf(-2.0f, acc[t][reg], ne);
                asm volatile("" : "+v"(g));       /* pin: identical bits both passes */
                if (PASS == 1) {
                    m[t][reg] = fminf(m[t][reg], g);
                } else if (g <= thr_r[t][reg]) {
                    const unsigned idx = atomicAdd(&rowcnt[row_r[t][reg]], 1u);
                    if (idx < CAND_CAP)
                        candrow[(size_t)row_r[t][reg] * CAND_CAP + idx] = (unsigned short)c;
                }
            }
        }
    }
    if (PASS == 1) {
#pragma unroll
        for (int t = 0; t < RT; ++t)
#pragma unroll
            for (int reg = 0; reg < 4; ++reg) {
                float v = m[t][reg];
                v = fminf(v, __shfl_xor(v, 1));
                v = fminf(v, __shfl_xor(v, 2));
                v = fminf(v, __shfl_xor(v, 4));
                v = fminf(v, __shfl_xor(v, 8));
                if (cl == 0) rowmin[row_r[t][reg]] = fmono(v);
            }
    }
}

/* ---------- thresholds: thr = gmin + rigorous margin ---------- */
__global__ void vq_thr(const unsigned* __restrict__ rowmin, const float* __restrict__ srow,
                       const unsigned* __restrict__ nEmax, float* __restrict__ thr) {
    const int r = blockIdx.x * blockDim.x + threadIdx.x;
    if (r >= VQ_R) return;
    const float nem = fmono_dec(*nEmax);
    const float margin = 8.0f * EPSREL * sqrtf(srow[r] * nem) + 2e-4f;
    thr[r] = fmono_dec(rowmin[r]) + margin;
}

/* ---------- exact phase: bit-exact D for survivors, (D,c)-min ---------- */
__global__ __launch_bounds__(MAIN_BLOCK) void vq_exact(
    const float* __restrict__ z, const float* __restrict__ emb,
    const float* __restrict__ nE, const unsigned* __restrict__ rowcnt,
    const unsigned short* __restrict__ candrow, float* __restrict__ out,
    float* __restrict__ partials) {
    const int r = blockIdx.x * MAIN_BLOCK + threadIdx.x;
    const int b = r >> 12;
    const int l = r & (VQ_L - 1);
    const float* zp = z + ((size_t)b << 18) + l;

    /* szz: numpy pairwise (8 accs, d=8i+j ascending, squares pre-rounded) */
    float a8[8];
#pragma unroll
    for (int j = 0; j < 8; ++j) {
        const float v = zp[(size_t)j << 12];
        float s = v * v;
        asm volatile("" : "+v"(s));
        a8[j] = s;
    }
#pragma unroll
    for (int i = 1; i < 8; ++i) {
#pragma unroll
        for (int j = 0; j < 8; ++j) {
            const float v = zp[(size_t)(8 * i + j) << 12];
            float s = v * v;
            asm volatile("" : "+v"(s));
            a8[j] += s;
        }
    }
    const float szz = ((a8[0] + a8[1]) + (a8[2] + a8[3]))
                    + ((a8[4] + a8[5]) + (a8[6] + a8[7]));

    unsigned long long best = ~0ull;
    const unsigned cnt = rowcnt[r];
    if (cnt >= 1u && cnt <= (unsigned)CAND_CAP) {
        for (unsigned i = 0; i < cnt; ++i) {
            const int c = candrow[(size_t)r * CAND_CAP + i];
            const float* __restrict__ ec = emb + (c << 6);
            float acc = 0.0f;
#pragma unroll
            for (int k = 0; k < VQ_D; ++k)
                acc = __builtin_fmaf(zp[(size_t)k << 12], ec[k], acc);
            const float D = (szz - 2.0f * acc) + nE[c];
            const unsigned long long key = ((unsigned long long)fmono(D) << 32) | (unsigned)c;
            best = (key < best) ? key : best;
        }
    } else {  /* overflow or anomaly: validated full exact scan */
        for (int c = 0; c < VQ_N; ++c) {
            const float* __restrict__ ec = emb + (c << 6);
            float acc = 0.0f;
#pragma unroll
            for (int k = 0; k < VQ_D; ++k)
                acc = __builtin_fmaf(zp[(size_t)k << 12], ec[k], acc);
            const float D = (szz - 2.0f * acc) + nE[c];
            const unsigned long long key = ((unsigned long long)fmono(D) << 32) | (unsigned)c;
            best = (key < best) ? key : best;
        }
    }
    const int bc = (int)(best & 0xFFFFFFFFull);

    const float* __restrict__ eb = emb + (bc << 6);
    float lsum = 0.0f;
#pragma unroll
    for (int d = 0; d < VQ_D; ++d) {
        const float q = eb[d];
        const float zd = zp[(size_t)d << 12];
        out[((size_t)b << 18) + ((size_t)d << 12) + l] = q;
        const float df = q - zd;
        lsum = __builtin_fmaf(df, df, lsum);
    }
    out[VQ_ZQ + 1 + (size_t)r] = (float)bc;

#pragma unroll
    for (int off = 32; off > 0; off >>= 1)
        lsum += __shfl_down(lsum, off, 64);
    __shared__ float wsum[MAIN_BLOCK / 64];
    const int lane = threadIdx.x & 63;
    const int wid = threadIdx.x >> 6;
    if (lane == 0) wsum[wid] = lsum;
    __syncthreads();
    if (threadIdx.x == 0)
        partials[blockIdx.x] = (wsum[0] + wsum[1]) + (wsum[2] + wsum[3]);
}

__global__ void vq_final(const float* __restrict__ partials, float* __restrict__ out) {
    if (threadIdx.x == 0 && blockIdx.x == 0) {
        float s = 0.0f;
        for (int i = 0; i < MAIN_GRID; ++i) s += partials[i];
        const float mse = s / (float)VQ_ZQ;
        out[VQ_ZQ] = mse + 0.25f * mse;
    }
}

/* ================= fallback path (round-8, validated, ~335us) ========== */
__global__ void vq_norme_fb(const float* __restrict__ emb, float* __restrict__ nEf) {
    const int c = blockIdx.x * blockDim.x + threadIdx.x;
    if (c >= VQ_N) return;
    const float* ec = emb + (c << 6);
    f32x16 zvA, zvB, zvC, zvD;
#pragma unroll
    for (int d = 0; d < 16; ++d) {
        zvA[d] = ec[d]; zvB[d] = ec[d + 16]; zvC[d] = ec[d + 32]; zvD[d] = ec[d + 48];
    }
    float s;
    NP_PAIRWISE64_SQ(s);
    nEf[c] = s;
}
__global__ __launch_bounds__(256, 4) void vq_dist_fb(
    const float* __restrict__ z, const float* __restrict__ emb,
    const float* __restrict__ nEf, float2* __restrict__ cand) {
    __shared__ float zs[VQ_D * 64];
    const int w = threadIdx.x >> 6;
    const int lane = threadIdx.x & 63;
    const int r = blockIdx.x * 64 + lane;
    const int b = r >> 12;
    const int l = r & (VQ_L - 1);
    const float* zp = z + ((size_t)b << 18) + l;
#pragma unroll
    for (int j = 0; j < 16; ++j) {
        const int d = (w << 4) + j;
        zs[d * 64 + lane] = zp[(size_t)d << 12];
    }
    __syncthreads();
    float a8[8];
#pragma unroll
    for (int j = 0; j < 8; ++j) {
        const float v = zs[j * 64 + lane];
        float s = v * v; asm volatile("" : "+v"(s)); a8[j] = s;
    }
#pragma unroll
    for (int i = 1; i < 8; ++i) {
#pragma unroll
        for (int j = 0; j < 8; ++j) {
            const float v = zs[(8 * i + j) * 64 + lane];
            float s = v * v; asm volatile("" : "+v"(s)); a8[j] += s;
        }
    }
    const float szz = ((a8[0] + a8[1]) + (a8[2] + a8[3])) + ((a8[4] + a8[5]) + (a8[6] + a8[7]));
    const int c0 = __builtin_amdgcn_readfirstlane(w) * 256;
    float best = __builtin_inff();
    int bc = c0;
    for (int t = 0; t < 256; t += 16) {
        float acc[16];
#pragma unroll
        for (int j = 0; j < 16; ++j) acc[j] = 0.0f;
#pragma unroll
        for (int kk = 0; kk < VQ_D; kk += 4) {
            const float z0 = zs[(kk + 0) * 64 + lane];
            const float z1 = zs[(kk + 1) * 64 + lane];
            const float z2 = zs[(kk + 2) * 64 + lane];
            const float z3 = zs[(kk + 3) * 64 + lane];
#pragma unroll
            for (int j = 0; j < 16; ++j) {
                const float* __restrict__ ec = emb + ((c0 + t + j) << 6) + kk;
                acc[j] = __builtin_fmaf(z0, ec[0], acc[j]);
                acc[j] = __builtin_fmaf(z1, ec[1], acc[j]);
                acc[j] = __builtin_fmaf(z2, ec[2], acc[j]);
                acc[j] = __builtin_fmaf(z3, ec[3], acc[j]);
            }
        }
#pragma unroll
        for (int j = 0; j < 16; ++j) {
            const int c = c0 + t + j;
            const float dist = (szz - 2.0f * acc[j]) + nEf[c];
            if (dist < best) { best = dist; bc = c; }
        }
    }
    cand[(size_t)w * VQ_R + r] = make_float2(best, (float)bc);
}
__global__ __launch_bounds__(MAIN_BLOCK) void vq_epilogue_fb(
    const float* __restrict__ z, const float* __restrict__ emb,
    const float2* __restrict__ cand, float* __restrict__ out,
    float* __restrict__ partials) {
    const int r = blockIdx.x * MAIN_BLOCK + threadIdx.x;
    const int b = r >> 12;
    const int l = r & (VQ_L - 1);
    float best = __builtin_inff();
    int bc = 0;
#pragma unroll
    for (int seg = 0; seg < 4; ++seg) {
        const float2 cd = cand[(size_t)seg * VQ_R + r];
        if (cd.x < best) { best = cd.x; bc = (int)cd.y; }
    }
    const float* zp = z + ((size_t)b << 18) + l;
    const float* __restrict__ eb = emb + (bc << 6);
    float lsum = 0.0f;
#pragma unroll
    for (int d = 0; d < VQ_D; ++d) {
        const float q = eb[d];
        const float zd = zp[(size_t)d << 12];
        out[((size_t)b << 18) + ((size_t)d << 12) + l] = q;
        const float df = q - zd;
        lsum = __builtin_fmaf(df, df, lsum);
    }
    out[VQ_ZQ + 1 + (size_t)r] = (float)bc;
#pragma unroll
    for (int off = 32; off > 0; off >>= 1)
        lsum += __shfl_down(lsum, off, 64);
    __shared__ float wsum[MAIN_BLOCK / 64];
    const int lane = threadIdx.x & 63;
    const int wid = threadIdx.x >> 6;
    if (lane == 0) wsum[wid] = lsum;
    __syncthreads();
    if (threadIdx.x == 0)
        partials[blockIdx.x] = (wsum[0] + wsum[1]) + (wsum[2] + wsum[3]);
}

/* ================= launch ================= */
extern "C" void kernel_launch(void* const* d_in, const int* in_sizes, int n_in,
                              void* d_out, int out_size, void* d_ws, size_t ws_size,
                              hipStream_t stream) {
    const float* z   = (const float*)d_in[0];
    const float* emb = (const float*)d_in[1];
    float* out = (float*)d_out;
    char* ws = (char*)d_ws;

    /* layout (16B-aligned) */
    unsigned short* z_bf   = (unsigned short*)(ws);                       /* 16777216 B */
    unsigned short* emb_bf = (unsigned short*)(ws + 16777216);            /*   131072 B */
    unsigned short* candrw = (unsigned short*)(ws + 16908288);            /*  4194304 B */
    unsigned*       rowmin = (unsigned*)(ws + 21102592);                  /*   524288 B */
    float*          thr    = (float*)(ws + 21626880);                     /*   524288 B */
    float*          srow   = (float*)(ws + 22151168);                     /*   524288 B */
    unsigned*       rowcnt = (unsigned*)(ws + 22675456);                  /*   524288 B */
    float*          nE     = (float*)(ws + 23199744);                     /*     4096 B */
    float*          parts  = (float*)(ws + 23203840);                     /*     2048 B */
    unsigned*       nEmax  = (unsigned*)(ws + 23205888);                  /*        4 B */
    const size_t need = 23205952;

    if (ws_size >= need) {
        vq_init<<<dim3(512), dim3(256), 0, stream>>>(rowcnt, nEmax);
        vq_prep_emb<<<dim3(4), dim3(256), 0, stream>>>(emb, nE, emb_bf, nEmax);
        vq_prep_z<<<dim3(512), dim3(256), 0, stream>>>(z, z_bf, srow);
        vq_gemm<1><<<dim3(VQ_R / 256), dim3(256), 0, stream>>>(z_bf, emb_bf, nE, thr,
                                                               rowmin, rowcnt, candrw);
        vq_thr<<<dim3(512), dim3(256), 0, stream>>>(rowmin, srow, nEmax, thr);
        vq_gemm<2><<<dim3(VQ_R / 256), dim3(256), 0, stream>>>(z_bf, emb_bf, nE, thr,
                                                               rowmin, rowcnt, candrw);
        vq_exact<<<dim3(MAIN_GRID), dim3(MAIN_BLOCK), 0, stream>>>(z, emb, nE, rowcnt,
                                                                   candrw, out, parts);
        vq_final<<<dim3(1), dim3(64), 0, stream>>>(parts, out);
    } else {
        /* validated round-8 fallback (~4.2 MB ws) */
        float* nEf = (float*)ws;
        float* partials = nEf + VQ_N;
        float2* cand = (float2*)(partials + MAIN_GRID);
        vq_norme_fb<<<dim3(4), dim3(256), 0, stream>>>(emb, nEf);
        vq_dist_fb<<<dim3(VQ_R / 64), dim3(256), 0, stream>>>(z, emb, nEf, cand);
        vq_epilogue_fb<<<dim3(MAIN_GRID), dim3(MAIN_BLOCK), 0, stream>>>(z, emb, cand, out, partials);
        vq_final<<<dim3(1), dim3(64), 0, stream>>>(partials, out);
    }
}